// Round 20
// baseline (122.297 us; speedup 1.0000x reference)
//
#include <hip/hip_runtime.h>
#include <hip/hip_bf16.h>
#include <stdint.h>

#define NBS 2
#define SEQ 2048
#define DMODEL 1024
#define NH 16
#define DHEAD 64
#define MROWS (NBS*SEQ)     // 4096
#define NQKV (NH*3*DHEAD)   // 3072

typedef __bf16 bf16;
typedef __bf16 bf16x8 __attribute__((ext_vector_type(8)));
typedef float f32x4 __attribute__((ext_vector_type(4)));
typedef float f32x16 __attribute__((ext_vector_type(16)));
typedef unsigned int u32x2 __attribute__((ext_vector_type(2)));

#define LOG2E 1.44269504088896f
#define QSCALE (0.125f * LOG2E)
#define KSTR 72   // attn LDS row stride (pad: 144B, 16B-aligned, 0 conflicts)

static __device__ __forceinline__ void gload_lds16(const bf16* g, bf16* l) {
    __builtin_amdgcn_global_load_lds(
        (const __attribute__((address_space(1))) uint32_t*)g,
        (__attribute__((address_space(3))) uint32_t*)l, 16, 0, 0);
}

static __device__ __forceinline__ bf16x8 ld_b8(const bf16* p) {
    return __builtin_bit_cast(bf16x8, *(const uint4*)p);
}

static __device__ __forceinline__ uint32_t pk_bf16(float lo, float hi) {
    unsigned short l = __builtin_bit_cast(unsigned short, (bf16)lo);
    unsigned short h = __builtin_bit_cast(unsigned short, (bf16)hi);
    return ((uint32_t)h << 16) | (uint32_t)l;
}

static __device__ __forceinline__ u32x2 lane_swap32(uint32_t a, uint32_t b, int lane) {
#if __has_builtin(__builtin_amdgcn_permlane32_swap)
    return __builtin_amdgcn_permlane32_swap(a, b, false, false);
#else
    uint32_t sa = __shfl_xor(a, 32), sb = __shfl_xor(b, 32);
    u32x2 r;
    r.x = (lane >= 32) ? sb : a;
    r.y = (lane >= 32) ? b : sa;
    return r;
#endif
}

// ---------------- fused prep: x->bf16, w_qkv permuted-T, w_out T ----------------
__global__ __launch_bounds__(256) void k_prep(
        const float* __restrict__ x, const float* __restrict__ w_qkv,
        const float* __restrict__ w_out,
        bf16* __restrict__ xb, bf16* __restrict__ wqkT, bf16* __restrict__ woT) {
    __shared__ float t[32][33];
    int bid = blockIdx.x, tid = threadIdx.x;
    if (bid < 4096) {
        int i = bid * 256 + tid;
        float4 v = ((const float4*)x)[i];
        ushort4 o;
        o.x = __builtin_bit_cast(unsigned short, (bf16)v.x);
        o.y = __builtin_bit_cast(unsigned short, (bf16)v.y);
        o.z = __builtin_bit_cast(unsigned short, (bf16)v.z);
        o.w = __builtin_bit_cast(unsigned short, (bf16)v.w);
        ((ushort4*)xb)[i] = o;
    } else if (bid < 7168) {
        int lb = bid - 4096;
        int bx = lb % 96, by = lb / 96;        // (NQKV/32, DMODEL/32)
        int tx = tid & 31, ty = tid >> 5;
        int r0 = by * 32, c0 = bx * 32;
#pragma unroll
        for (int i = 0; i < 4; i++)
            t[ty + i*8][tx] = w_qkv[(size_t)(r0 + ty + i*8) * NQKV + (c0 + tx)];
        __syncthreads();
#pragma unroll
        for (int i = 0; i < 4; i++) {
            int c = c0 + ty + i*8;
            int h = c / 192, f = c % 192;
            int cperm = ((f >> 6) << 10) + (h << 6) + (f & 63);
            wqkT[(size_t)cperm * DMODEL + (r0 + tx)] = (bf16)t[tx][ty + i*8];
        }
    } else {
        int lb = bid - 7168;
        int bx = lb & 31, by = lb >> 5;        // (DMODEL/32, DMODEL/32)
        int tx = tid & 31, ty = tid >> 5;
        int r0 = by * 32, c0 = bx * 32;
#pragma unroll
        for (int i = 0; i < 4; i++)
            t[ty + i*8][tx] = w_out[(size_t)(r0 + ty + i*8) * DMODEL + (c0 + tx)];
        __syncthreads();
#pragma unroll
        for (int i = 0; i < 4; i++)
            woT[(size_t)(c0 + ty + i*8) * DMODEL + (r0 + tx)] = (bf16)t[tx][ty + i*8];
    }
}

// ---------------- GEMM1: 256x192 tile, BK=64, 512 thr, counted-vmcnt (R16) ----
#define G1_NT 16   // 1024/64 K-tiles

__global__ __launch_bounds__(512, 2) void k_gemm_qkv(
        const bf16* __restrict__ A, const bf16* __restrict__ Bt,
        const float* __restrict__ bias,
        bf16* __restrict__ Q, bf16* __restrict__ Kp, bf16* __restrict__ Vt) {
    __shared__ __align__(16) bf16 As[2][256*64];
    __shared__ __align__(16) bf16 Bs[2][192*64];
    int tid = threadIdx.x;
    int wid = tid >> 6, lane = tid & 63;
    int wr = wid >> 2, wc = wid & 3;
    int g = lane >> 4, r = lane & 15;

    int lid = blockIdx.y * 16 + blockIdx.x;
    int swz = (lid & 7) * 32 + (lid >> 3);
    int tile_n = (swz % 16) * 192, tile_m = (swz / 16) * 256;

    f32x4 acc[8][3];
#pragma unroll
    for (int m = 0; m < 8; m++)
#pragma unroll
        for (int n = 0; n < 3; n++)
            acc[m][n] = (f32x4){0.f, 0.f, 0.f, 0.f};

    int srowA[4], schkA[4], srowB[3], schkB[3];
#pragma unroll
    for (int j2 = 0; j2 < 4; j2++) {
        int idx = tid + j2 * 512;
        srowA[j2] = idx >> 3;
        schkA[j2] = ((idx & 7) ^ (srowA[j2] & 7)) * 8;
    }
#pragma unroll
    for (int j2 = 0; j2 < 3; j2++) {
        int idx = tid + j2 * 512;
        srowB[j2] = idx >> 3;
        schkB[j2] = ((idx & 7) ^ (srowB[j2] & 7)) * 8;
    }

#define G1_STAGE(buf, k0)                                                          \
    {                                                                              \
        _Pragma("unroll")                                                          \
        for (int j2 = 0; j2 < 4; j2++)                                             \
            gload_lds16(A + (size_t)(tile_m + srowA[j2]) * DMODEL + (k0) + schkA[j2], \
                        As[buf] + (tid + j2*512) * 8);                             \
        _Pragma("unroll")                                                          \
        for (int j2 = 0; j2 < 3; j2++)                                             \
            gload_lds16(Bt + (size_t)(tile_n + srowB[j2]) * DMODEL + (k0) + schkB[j2], \
                        Bs[buf] + (tid + j2*512) * 8);                             \
    }

    G1_STAGE(0, 0);

    int r7 = r & 7;
    for (int t = 0; t < G1_NT; t++) {
        int cur = t & 1;
        if (t + 1 < G1_NT) {
            G1_STAGE(cur ^ 1, (t + 1) * 64);
            asm volatile("s_waitcnt vmcnt(7)" ::: "memory");
        } else {
            asm volatile("s_waitcnt vmcnt(0)" ::: "memory");
        }
        __builtin_amdgcn_s_barrier();
        __builtin_amdgcn_sched_barrier(0);

        const bf16* pa = As[cur];
        const bf16* pb = Bs[cur];
#pragma unroll
        for (int kk = 0; kk < 2; kk++) {
            int rchk = ((kk*4 + g) ^ r7) * 8;
            bf16x8 bfr[3];
#pragma unroll
            for (int n = 0; n < 3; n++)
                bfr[n] = ld_b8(pb + (wc*48 + n*16 + r) * 64 + rchk);
#pragma unroll
            for (int m = 0; m < 8; m++) {
                bf16x8 af = ld_b8(pa + (wr*128 + m*16 + r) * 64 + rchk);
#pragma unroll
                for (int n = 0; n < 3; n++)
                    acc[m][n] = __builtin_amdgcn_mfma_f32_16x16x32_bf16(af, bfr[n], acc[m][n], 0, 0, 0);
            }
        }
        asm volatile("s_waitcnt lgkmcnt(0)" ::: "memory");
        __builtin_amdgcn_s_barrier();
    }

#pragma unroll
    for (int m = 0; m < 8; m++) {
#pragma unroll
        for (int n = 0; n < 3; n++) {
            int col = tile_n + wc*48 + n*16 + r;
            int kind = col >> 10;
            int h = (col >> 6) & 15;
            int d = col & 63;
            float bv = bias[h*192 + (kind << 6) + d];
            if (kind == 2) {
                int row0 = tile_m + wr*128 + m*16 + g*4;
                int b = row0 >> 11, s0 = row0 & 2047;
                ushort4 vv;
                vv.x = __builtin_bit_cast(unsigned short, (bf16)(acc[m][n][0] + bv));
                vv.y = __builtin_bit_cast(unsigned short, (bf16)(acc[m][n][1] + bv));
                vv.z = __builtin_bit_cast(unsigned short, (bf16)(acc[m][n][2] + bv));
                vv.w = __builtin_bit_cast(unsigned short, (bf16)(acc[m][n][3] + bv));
                *(ushort4*)&Vt[(((size_t)(b*NH + h)) * DHEAD + d) * SEQ + s0] = vv;
            } else {
#pragma unroll
                for (int j = 0; j < 4; j++) {
                    int row = tile_m + wr*128 + m*16 + g*4 + j;
                    int b = row >> 11, s = row & 2047;
                    float v = acc[m][n][j] + bv;
                    size_t addr = (((size_t)(b*NH + h)) * SEQ + s) * DHEAD + d;
                    if (kind == 0) Q[addr]  = (bf16)(v * QSCALE);
                    else           Kp[addr] = (bf16)v;
                }
            }
        }
    }
#undef G1_STAGE
}

// ---- gemm_out FUSED with merge: A computed from partials during staging ----
// A[row][col] = (Op0 + u1*Op1 + u2*Op2)[bh(b,h)][s][d] / l, qc block-uniform.
// A reg-staged (loads issued before MFMA phase -> latency hidden, T14);
// B via gload_lds; dbuf LDS; __syncthreads barriers.
__global__ __launch_bounds__(256) void k_gemm_out_f(
        const bf16* __restrict__ Op0, const bf16* __restrict__ Op1,
        const bf16* __restrict__ Op2,
        const float* __restrict__ Lp0, const float* __restrict__ Lp1,
        const float* __restrict__ Lp2,
        const bf16* __restrict__ Bt, const float* __restrict__ bias,
        float* __restrict__ out) {
    __shared__ __align__(16) bf16 As[2][64*32];
    __shared__ __align__(16) bf16 Bs[2][128*32];
    int tid = threadIdx.x;
    int wave = tid >> 6, lane = tid & 63;
    int g = lane >> 4, r = lane & 15;
    int srow = lane >> 2, schunk = (lane & 3) * 8;
    int tile_m = blockIdx.y * 64, tile_n = blockIdx.x * 128;

    int row = tile_m + wave*16 + srow;
    int b = row >> 11, s = row & 2047;
    int qc = s >> 7, sl = s & 127;                    // block-uniform qc
    int qc5  = (qc >= 5)  ? qc - 5  : 0;
    int qc11 = (qc >= 11) ? qc - 11 : 0;
    float u1 = (qc >= 5)  ? 1.f : 0.f;
    float u2 = (qc >= 11) ? 1.f : 0.f;
    int i1 = qc5*128 + sl, i2 = qc11*128 + sl;

    f32x4 acc[4][2];
#pragma unroll
    for (int m = 0; m < 4; m++)
#pragma unroll
        for (int n = 0; n < 2; n++)
            acc[m][n] = (f32x4){0.f, 0.f, 0.f, 0.f};

#define A_LOAD(t, p0v, p1v, p2v, l0v, l1v, l2v)                                   \
    {                                                                             \
        int h_ = (t) >> 1, d0_ = ((t) & 1) * 32 + schunk;                         \
        int bh_ = b*16 + h_;                                                      \
        p0v = *(const uint4*)&Op0[((size_t)bh_*2048 + s)*64 + d0_];               \
        p1v = *(const uint4*)&Op1[((size_t)bh_*1408 + i1)*64 + d0_];              \
        p2v = *(const uint4*)&Op2[((size_t)bh_*640  + i2)*64 + d0_];              \
        l0v = Lp0[bh_*2048 + s]; l1v = Lp1[bh_*1408 + i1]; l2v = Lp2[bh_*640 + i2]; \
    }

#define A_MERGE(buf, p0v, p1v, p2v, l0v, l1v, l2v)                                \
    {                                                                             \
        bf16x8 q0_ = __builtin_bit_cast(bf16x8, p0v);                             \
        bf16x8 q1_ = __builtin_bit_cast(bf16x8, p1v);                             \
        bf16x8 q2_ = __builtin_bit_cast(bf16x8, p2v);                             \
        float inv_ = 1.0f / (l0v + u1*l1v + u2*l2v);                              \
        bf16x8 mg_;                                                               \
        _Pragma("unroll")                                                         \
        for (int i_ = 0; i_ < 8; i_++)                                            \
            mg_[i_] = (bf16)((((float)q0_[i_]) + u1*(float)q1_[i_]                \
                              + u2*(float)q2_[i_]) * inv_);                       \
        *(uint4*)&As[buf][(wave*16 + srow)*32 + schunk] =                         \
            __builtin_bit_cast(uint4, mg_);                                       \
    }

#define B_STAGE(buf, k0)                                                                  \
    {                                                                                     \
        gload_lds16(Bt + (size_t)(tile_n + wave*16 + srow) * DMODEL + (k0) + schunk,      \
                    Bs[buf] + wave*512);                                                  \
        gload_lds16(Bt + (size_t)(tile_n + 64 + wave*16 + srow) * DMODEL + (k0) + schunk, \
                    Bs[buf] + 2048 + wave*512);                                           \
    }

    uint4 pa0, pa1, pa2;
    float la0, la1, la2;

    // prologue: tile 0
    A_LOAD(0, pa0, pa1, pa2, la0, la1, la2);
    B_STAGE(0, 0);
    A_MERGE(0, pa0, pa1, pa2, la0, la1, la2);
    __syncthreads();

    for (int t = 0; t < 32; t++) {
        int cur = t & 1;
        if (t + 1 < 32) {
            A_LOAD(t + 1, pa0, pa1, pa2, la0, la1, la2);   // issue early
            B_STAGE(cur ^ 1, (t + 1) * 32);
        }
        bf16x8 af[4], bfr[2];
#pragma unroll
        for (int m = 0; m < 4; m++) af[m]  = *(const bf16x8*)(As[cur] + (m*16 + r)*32 + g*8);
#pragma unroll
        for (int n = 0; n < 2; n++) bfr[n] = *(const bf16x8*)(Bs[cur] + (wave*32 + n*16 + r)*32 + g*8);
#pragma unroll
        for (int m = 0; m < 4; m++)
#pragma unroll
            for (int n = 0; n < 2; n++)
                acc[m][n] = __builtin_amdgcn_mfma_f32_16x16x32_bf16(af[m], bfr[n], acc[m][n], 0, 0, 0);
        if (t + 1 < 32)
            A_MERGE(cur ^ 1, pa0, pa1, pa2, la0, la1, la2);  // waits A loads (hidden)
        __syncthreads();
    }
#undef A_LOAD
#undef A_MERGE
#undef B_STAGE

#pragma unroll
    for (int m = 0; m < 4; m++) {
#pragma unroll
        for (int n = 0; n < 2; n++) {
            int col = tile_n + wave*32 + n*16 + r;
            float bv = bias[col];
#pragma unroll
            for (int j = 0; j < 4; j++) {
                int orow = tile_m + m*16 + g*4 + j;
                out[(size_t)orow * DMODEL + col] = acc[m][n][j] + bv;
            }
        }
    }
}

// ---- gemm_out (plain A-read, fallback path) ----
__global__ __launch_bounds__(256) void k_gemm_out(
        const bf16* __restrict__ A, const bf16* __restrict__ Bt,
        const float* __restrict__ bias, float* __restrict__ out) {
    __shared__ __align__(16) bf16 As[2][64*32];
    __shared__ __align__(16) bf16 Bs[2][128*32];
    int tid = threadIdx.x;
    int wave = tid >> 6, lane = tid & 63;
    int g = lane >> 4, r = lane & 15;
    int srow = lane >> 2, schunk = (lane & 3) * 8;
    int tile_m = blockIdx.y * 64, tile_n = blockIdx.x * 128;

    f32x4 acc[4][2];
#pragma unroll
    for (int m = 0; m < 4; m++)
#pragma unroll
        for (int n = 0; n < 2; n++)
            acc[m][n] = (f32x4){0.f, 0.f, 0.f, 0.f};

#define GO_STAGE(buf, k0)                                                                 \
    {                                                                                     \
        gload_lds16(A  + (size_t)(tile_m + wave*16 + srow) * DMODEL + (k0) + schunk,      \
                    As[buf] + wave*512);                                                  \
        gload_lds16(Bt + (size_t)(tile_n + wave*16 + srow) * DMODEL + (k0) + schunk,      \
                    Bs[buf] + wave*512);                                                  \
        gload_lds16(Bt + (size_t)(tile_n + 64 + wave*16 + srow) * DMODEL + (k0) + schunk, \
                    Bs[buf] + 2048 + wave*512);                                           \
    }

    GO_STAGE(0, 0);

    for (int t = 0; t < 32; t++) {
        int cur = t & 1;
        if (t + 1 < 32) {
            GO_STAGE(cur ^ 1, (t + 1) * 32);
            asm volatile("s_waitcnt vmcnt(3)" ::: "memory");
        } else {
            asm volatile("s_waitcnt vmcnt(0)" ::: "memory");
        }
        __builtin_amdgcn_s_barrier();
        __builtin_amdgcn_sched_barrier(0);

        bf16x8 af[4], bfr[2];
#pragma unroll
        for (int m = 0; m < 4; m++) af[m]  = *(const bf16x8*)(As[cur] + (m*16 + r)*32 + g*8);
#pragma unroll
        for (int n = 0; n < 2; n++) bfr[n] = *(const bf16x8*)(Bs[cur] + (wave*32 + n*16 + r)*32 + g*8);
#pragma unroll
        for (int m = 0; m < 4; m++)
#pragma unroll
            for (int n = 0; n < 2; n++)
                acc[m][n] = __builtin_amdgcn_mfma_f32_16x16x32_bf16(af[m], bfr[n], acc[m][n], 0, 0, 0);
        asm volatile("s_waitcnt lgkmcnt(0)" ::: "memory");
        __builtin_amdgcn_s_barrier();
    }
#undef GO_STAGE

#pragma unroll
    for (int m = 0; m < 4; m++) {
#pragma unroll
        for (int n = 0; n < 2; n++) {
            int col = tile_n + wave*32 + n*16 + r;
            float bv = bias[col];
#pragma unroll
            for (int j = 0; j < 4; j++) {
                int row = tile_m + m*16 + g*4 + j;
                out[(size_t)row * DMODEL + col] = acc[m][n][j] + bv;
            }
        }
    }
}

// ---------------- flash attention: pad-72 LDS (43.4us plateau config) --------
#define QBLK 128
#define KVB 64

static __device__ __forceinline__ void attn_tile_body(
        const bf16* Ks, const bf16* VsT,
        const bf16x8 qa2[4], const bf16x8& ones,
        f32x16 o32[2], f32x16& acc_l,
        int kv0, int qb, int qrow, int l31, int hi, int lane) {
    const f32x16 z16 = {0,0,0,0,0,0,0,0,0,0,0,0,0,0,0,0};
    f32x16 st[2];
    st[0] = z16; st[1] = z16;
    __builtin_amdgcn_s_setprio(1);
#pragma unroll
    for (int c = 0; c < 4; c++) {
        bf16x8 kf0 = ld_b8(Ks + l31*KSTR        + c*16 + hi*8);
        bf16x8 kf1 = ld_b8(Ks + (32 + l31)*KSTR + c*16 + hi*8);
        st[0] = __builtin_amdgcn_mfma_f32_32x32x16_bf16(kf0, qa2[c], st[0], 0, 0, 0);
        st[1] = __builtin_amdgcn_mfma_f32_32x32x16_bf16(kf1, qa2[c], st[1], 0, 0, 0);
    }
    __builtin_amdgcn_s_setprio(0);

    bf16x8 vf[2][4];
#pragma unroll
    for (int dblk = 0; dblk < 2; dblk++)
#pragma unroll
        for (int c = 0; c < 4; c++)
            vf[dblk][c] = ld_b8(VsT + (dblk*32 + l31)*KSTR + c*16 + hi*8);

    bool needm = (kv0 + KVB - 1) > qb;
#pragma unroll
    for (int rb = 0; rb < 2; rb++) {
#pragma unroll
        for (int reg = 0; reg < 16; reg++) {
            float e = __builtin_amdgcn_exp2f(st[rb][reg]);
            if (needm) {
                int kv = kv0 + rb*32 + (reg & 3) + 8*(reg >> 2) + 4*hi;
                if (kv > qrow) e = 0.f;
            }
            st[rb][reg] = e;
        }
    }

    bf16x8 pa[4];
#pragma unroll
    for (int c = 0; c < 4; c++) {
        const f32x16& pp = st[c >> 1];
        const int base = (c & 1) * 8;
        uint32_t a0 = pk_bf16(pp[base+0], pp[base+1]);
        uint32_t a1 = pk_bf16(pp[base+2], pp[base+3]);
        uint32_t b0 = pk_bf16(pp[base+4], pp[base+5]);
        uint32_t b1 = pk_bf16(pp[base+6], pp[base+7]);
        u32x2 s0 = lane_swap32(a0, b0, lane);
        u32x2 s1 = lane_swap32(a1, b1, lane);
        uint4 fr = {s0.x, s1.x, s0.y, s1.y};
        pa[c] = __builtin_bit_cast(bf16x8, fr);
    }

    __builtin_amdgcn_s_setprio(1);
#pragma unroll
    for (int c = 0; c < 4; c++) {
        o32[0] = __builtin_amdgcn_mfma_f32_32x32x16_bf16(pa[c], vf[0][c], o32[0], 0, 0, 0);
        o32[1] = __builtin_amdgcn_mfma_f32_32x32x16_bf16(pa[c], vf[1][c], o32[1], 0, 0, 0);
        acc_l  = __builtin_amdgcn_mfma_f32_32x32x16_bf16(pa[c], ones, acc_l, 0, 0, 0);
    }
    __builtin_amdgcn_s_setprio(0);
}

// ---- equal-length job tables ----
__device__ const int8_t JQC[32]  = {10,10, 4, 0, 15,15, 3, 1,  9, 9, 7, 2, 13,14, 7, 5,
                                    14,14,11, 5, 15, 8,11, 6,  8,12,12, 6, 13,13,11,12};
__device__ const int8_t JT0[32]  = { 0,11, 0, 0,  0,11, 0, 0,  0,10, 0, 0,  0, 0, 8, 0,
                                    10,20, 0, 6, 22, 0, 8, 0,  9, 0, 9, 7, 10,19,16,18};
__device__ const int8_t JT1[32]  = {11,22,10, 2, 11,22, 8, 4, 10,20, 8, 6, 10,10,16, 6,
                                    20,30, 8,12, 32, 9,16, 7, 18, 9,18,14, 19,28,24,26};
__device__ const int8_t JSEG[32] = { 0, 1, 0, 0,  0, 1, 0, 0,  0, 1, 0, 0,  0, 0, 1, 0,
                                     1, 2, 0, 1,  2, 0, 1, 0,  1, 0, 1, 1,  1, 2, 2, 2};

__global__ __launch_bounds__(256) void k_attn_split(
        const bf16* __restrict__ Q, const bf16* __restrict__ K,
        const bf16* __restrict__ Vt,
        bf16* __restrict__ Op0, bf16* __restrict__ Op1, bf16* __restrict__ Op2,
        float* __restrict__ Lp0, float* __restrict__ Lp1, float* __restrict__ Lp2) {
    int scu = blockIdx.x;
    int bh = scu >> 3, slot = scu & 7;
    int j = slot * 4 + blockIdx.y;
    int qc  = JQC[j];
    int t0  = JT0[j];
    int t1  = JT1[j];
    int seg = JSEG[j];
    int q0 = qc * QBLK;
    int tid = threadIdx.x, wave = tid >> 6, lane = tid & 63;
    int l31 = lane & 31, hi = lane >> 5;

    __shared__ __align__(16) bf16 Ks[2][KVB*KSTR];
    __shared__ __align__(16) bf16 VsT[2][KVB*KSTR];

    const bf16* Kg = K  + (size_t)bh * SEQ * DHEAD;
    const bf16* Vg = Vt + (size_t)bh * DHEAD * SEQ;

    int qb = q0 + wave * 32;
    int qrow = qb + l31;

    const bf16* qrow_p = Q + ((size_t)bh * SEQ + qrow) * DHEAD;
    bf16x8 qa2[4];
#pragma unroll
    for (int c = 0; c < 4; c++) qa2[c] = ld_b8(qrow_p + c*16 + hi*8);

    bf16x8 ones;
#pragma unroll
    for (int c = 0; c < 8; c++) ones[c] = (bf16)1.0f;

    const f32x16 z16 = {0,0,0,0,0,0,0,0,0,0,0,0,0,0,0,0};
    f32x16 o32[2], acc_l;
    o32[0] = z16; o32[1] = z16; acc_l = z16;

    int qmax_wave = qb + 31;

    int srow = tid >> 3, sc8 = (tid & 7) * 8;
    int wK0 = srow*KSTR + sc8;
    int wK1 = (srow+32)*KSTR + sc8;

    bf16x8 kreg[2], vreg[2];
    {
        int kvs = t0 * KVB;
        kreg[0] = ld_b8(Kg + (size_t)(kvs + srow)      * DHEAD + sc8);
        kreg[1] = ld_b8(Kg + (size_t)(kvs + srow + 32) * DHEAD + sc8);
        vreg[0] = ld_b8(Vg + (size_t)srow      * SEQ + kvs + sc8);
        vreg[1] = ld_b8(Vg + (size_t)(srow+32) * SEQ + kvs + sc8);
    }

    int cur = 0;
    for (int t = t0; t < t1; t++) {
        int kv0 = t * KVB;
        *(uint4*)&Ks[cur][wK0]  = __builtin_bit_cast(uint4, kreg[0]);
        *(uint4*)&Ks[cur][wK1]  = __builtin_bit_cast(uint4, kreg[1]);
        *(uint4*)&VsT[cur][wK0] = __builtin_bit_cast(uint4, vreg[0]);
        *(uint4*)&VsT[cur][wK1] = __builtin_bit_cast(uint4, vreg[1]);
        __syncthreads();

        if (t + 1 < t1) {
            int kv1 = kv0 + KVB;
            kreg[0] = ld_b8(Kg + (size_t)(kv1 + srow)      * DHEAD + sc8);
            kreg[1] = ld_b8(Kg + (size_t)(kv1 + srow + 32) * DHEAD + sc8);
            vreg[0] = ld_b8(Vg + (size_t)srow      * SEQ + kv1 + sc8);
            vreg[1] = ld_b8(Vg + (size_t)(srow+32) * SEQ + kv1 + sc8);
        }

        if (kv0 <= qmax_wave)
            attn_tile_body(Ks[cur], VsT[cur], qa2, ones, o32, acc_l,
                           kv0, qb, qrow, l31, hi, lane);
        cur ^= 1;
    }

    bf16* Op; float* Lp; size_t obase; int lbase;
    if (seg == 0)      { Op = Op0; Lp = Lp0; obase = ((size_t)bh*2048 + q0) * 64;          lbase = bh*2048 + q0; }
    else if (seg == 1) { Op = Op1; Lp = Lp1; obase = ((size_t)bh*1408 + (qc-5)*128) * 64;  lbase = bh*1408 + (qc-5)*128; }
    else               { Op = Op2; Lp = Lp2; obase = ((size_t)bh*640  + (qc-11)*128) * 64; lbase = bh*640  + (qc-11)*128; }

    if (l31 == 0) {
#pragma unroll
        for (int reg = 0; reg < 16; reg++) {
            int qr = (reg & 3) + 8*(reg >> 2) + 4*hi;
            Lp[lbase + wave*32 + qr] = acc_l[reg];
        }
    }

#pragma unroll
    for (int reg = 0; reg < 16; reg++) {
        int qr = (reg & 3) + 8*(reg >> 2) + 4*hi;
        size_t base = obase + (size_t)(wave*32 + qr) * 64 + l31;
        Op[base]      = (bf16)o32[0][reg];
        Op[base + 32] = (bf16)o32[1][reg];
    }
}

// ---- fallback single-pass attention for small ws ----
__global__ __launch_bounds__(256) void k_attn(
        const bf16* __restrict__ Q, const bf16* __restrict__ K,
        const bf16* __restrict__ Vt, bf16* __restrict__ O) {
    int bh = blockIdx.y;
    int qc = (bh >= 16) ? (15 - (int)blockIdx.x) : (int)blockIdx.x;
    int q0 = qc * QBLK;
    int tid = threadIdx.x, wave = tid >> 6, lane = tid & 63;
    int l31 = lane & 31, hi = lane >> 5;

    __shared__ __align__(16) bf16 Ks[2][KVB*KSTR];
    __shared__ __align__(16) bf16 VsT[2][KVB*KSTR];

    const bf16* Kg = K  + (size_t)bh * SEQ * DHEAD;
    const bf16* Vg = Vt + (size_t)bh * DHEAD * SEQ;

    int qb = q0 + wave * 32;
    int qrow = qb + l31;

    const bf16* qrow_p = Q + ((size_t)bh * SEQ + qrow) * DHEAD;
    bf16x8 qa2[4];
#pragma unroll
    for (int c = 0; c < 4; c++) qa2[c] = ld_b8(qrow_p + c*16 + hi*8);

    bf16x8 ones;
#pragma unroll
    for (int c = 0; c < 8; c++) ones[c] = (bf16)1.0f;

    const f32x16 z16 = {0,0,0,0,0,0,0,0,0,0,0,0,0,0,0,0};
    f32x16 o32[2], acc_l;
    o32[0] = z16; o32[1] = z16; acc_l = z16;

    int nt = 2*qc + 2;
    int qmax_wave = qb + 31;

    int srow = tid >> 3, sc8 = (tid & 7) * 8;
    int wK0 = srow*KSTR + sc8;
    int wK1 = (srow+32)*KSTR + sc8;

    bf16x8 kreg[2], vreg[2];
    kreg[0] = ld_b8(Kg + (size_t)srow      * DHEAD + sc8);
    kreg[1] = ld_b8(Kg + (size_t)(srow+32) * DHEAD + sc8);
    vreg[0] = ld_b8(Vg + (size_t)srow      * SEQ + sc8);
    vreg[1] = ld_b8(Vg + (size_t)(srow+32) * SEQ + sc8);

    int cur = 0;
    for (int t = 0; t < nt; t++) {
        int kv0 = t * KVB;
        *(uint4*)&Ks[cur][wK0]  = __builtin_bit_cast(uint4, kreg[0]);
        *(uint4*)&Ks[cur][wK1]  = __builtin_bit_cast(uint4, kreg[1]);
        *(uint4*)&VsT[cur][wK0] = __builtin_bit_cast(uint4, vreg[0]);
        *(uint4*)&VsT[cur][wK1] = __builtin_bit_cast(uint4, vreg[1]);
        __syncthreads();

        if (t + 1 < nt) {
            int kv1 = kv0 + KVB;
            kreg[0] = ld_b8(Kg + (size_t)(kv1 + srow)      * DHEAD + sc8);
            kreg[1] = ld_b8(Kg + (size_t)(kv1 + srow + 32) * DHEAD + sc8);
            vreg[0] = ld_b8(Vg + (size_t)srow      * SEQ + kv1 + sc8);
            vreg[1] = ld_b8(Vg + (size_t)(srow+32) * SEQ + kv1 + sc8);
        }

        if (kv0 <= qmax_wave)
            attn_tile_body(Ks[cur], VsT[cur], qa2, ones, o32, acc_l,
                           kv0, qb, qrow, l31, hi, lane);
        cur ^= 1;
    }

    int b = bh >> 4, h = bh & 15;
#pragma unroll
    for (int reg = 0; reg < 16; reg++) {
        int qr = (reg & 3) + 8*(reg >> 2) + 4*hi;
        int srow2 = q0 + wave*32 + qr;
        float linv = 1.0f / acc_l[reg];
        size_t base = (((size_t)b * SEQ + srow2) * NH + h) * DHEAD + l31;
        O[base]      = (bf16)(o32[0][reg] * linv);
        O[base + 32] = (bf16)(o32[1][reg] * linv);
    }
}

// ---------------- launch ----------------

extern "C" void kernel_launch(void* const* d_in, const int* in_sizes, int n_in,
                              void* d_out, int out_size, void* d_ws, size_t ws_size,
                              hipStream_t stream) {
    const float* x     = (const float*)d_in[0];
    const float* w_qkv = (const float*)d_in[1];
    const float* b_qkv = (const float*)d_in[2];
    const float* w_out = (const float*)d_in[3];
    const float* b_out = (const float*)d_in[4];
    float* out = (float*)d_out;

    char* ws = (char*)d_ws;
    bf16* xb   = (bf16*)(ws);                      // 8.39MB; fallback attn output
    bf16* wqkT = (bf16*)(ws + 8388608);            // 6.29MB (dead after GEMM1 -> Lp)
    bf16* woT  = (bf16*)(ws + 14680064);           // 2.10MB
    bf16* qb   = (bf16*)(ws + 16777216);           // 8.39MB
    bf16* kb   = (bf16*)(ws + 25165824);           // 8.39MB
    bf16* vb   = (bf16*)(ws + 33554432);           // 8.39MB (V^T layout)
    bf16* Op0  = (bf16*)(ws + 41943040);           // 8.39MB (seg0, all qc)
    bf16* Op1  = (bf16*)(ws + 50331648);           // 5.77MB (seg1, qc>=5)
    bf16* Op2  = (bf16*)(ws + 56098816);           // 2.62MB (seg2, qc>=11)
    float* Lp0 = (float*)(ws + 8388608);           // in dead wqkT region
    float* Lp1 = (float*)(ws + 8388608 + 262144);
    float* Lp2 = (float*)(ws + 8388608 + 524288);
    const size_t WS_NEED = 58720256;
    bf16* attn = xb;                               // fallback path only

    k_prep<<<8192, 256, 0, stream>>>(x, w_qkv, w_out, xb, wqkT, woT);

    k_gemm_qkv<<<dim3(16, 16), 512, 0, stream>>>(xb, wqkT, b_qkv, qb, kb, vb);

    if (ws_size >= WS_NEED) {
        k_attn_split<<<dim3(256, 4), 256, 0, stream>>>(qb, kb, vb,
                                                       Op0, Op1, Op2, Lp0, Lp1, Lp2);
        k_gemm_out_f<<<dim3(DMODEL/128, MROWS/64), 256, 0, stream>>>(
            Op0, Op1, Op2, Lp0, Lp1, Lp2, woT, b_out, out);
    } else {
        k_attn<<<dim3(SEQ/QBLK, NBS*NH), 256, 0, stream>>>(qb, kb, vb, attn);
        k_gemm_out<<<dim3(DMODEL/128, MROWS/64), 256, 0, stream>>>(attn, woT, b_out, out);
    }
}

// Round 21
// 115.213 us; speedup vs baseline: 1.0615x; 1.0615x over previous
//
#include <hip/hip_runtime.h>
#include <hip/hip_bf16.h>
#include <stdint.h>

#define NBS 2
#define SEQ 2048
#define DMODEL 1024
#define NH 16
#define DHEAD 64
#define MROWS (NBS*SEQ)     // 4096
#define NQKV (NH*3*DHEAD)   // 3072

typedef __bf16 bf16;
typedef __bf16 bf16x8 __attribute__((ext_vector_type(8)));
typedef float f32x4 __attribute__((ext_vector_type(4)));
typedef float f32x16 __attribute__((ext_vector_type(16)));
typedef unsigned int u32x2 __attribute__((ext_vector_type(2)));

#define LOG2E 1.44269504088896f
#define QSCALE (0.125f * LOG2E)
#define KSTR 72   // attn LDS row stride (pad: 144B, 16B-aligned, 0 conflicts)

static __device__ __forceinline__ void gload_lds16(const bf16* g, bf16* l) {
    __builtin_amdgcn_global_load_lds(
        (const __attribute__((address_space(1))) uint32_t*)g,
        (__attribute__((address_space(3))) uint32_t*)l, 16, 0, 0);
}

static __device__ __forceinline__ bf16x8 ld_b8(const bf16* p) {
    return __builtin_bit_cast(bf16x8, *(const uint4*)p);
}

static __device__ __forceinline__ uint32_t pk_bf16(float lo, float hi) {
    unsigned short l = __builtin_bit_cast(unsigned short, (bf16)lo);
    unsigned short h = __builtin_bit_cast(unsigned short, (bf16)hi);
    return ((uint32_t)h << 16) | (uint32_t)l;
}

static __device__ __forceinline__ u32x2 lane_swap32(uint32_t a, uint32_t b, int lane) {
#if __has_builtin(__builtin_amdgcn_permlane32_swap)
    return __builtin_amdgcn_permlane32_swap(a, b, false, false);
#else
    uint32_t sa = __shfl_xor(a, 32), sb = __shfl_xor(b, 32);
    u32x2 r;
    r.x = (lane >= 32) ? sb : a;
    r.y = (lane >= 32) ? b : sa;
    return r;
#endif
}

// ---------------- fused prep: x->bf16, w_qkv permuted-T, w_out T ----------------
__global__ __launch_bounds__(256) void k_prep(
        const float* __restrict__ x, const float* __restrict__ w_qkv,
        const float* __restrict__ w_out,
        bf16* __restrict__ xb, bf16* __restrict__ wqkT, bf16* __restrict__ woT) {
    __shared__ float t[32][33];
    int bid = blockIdx.x, tid = threadIdx.x;
    if (bid < 4096) {
        int i = bid * 256 + tid;
        float4 v = ((const float4*)x)[i];
        ushort4 o;
        o.x = __builtin_bit_cast(unsigned short, (bf16)v.x);
        o.y = __builtin_bit_cast(unsigned short, (bf16)v.y);
        o.z = __builtin_bit_cast(unsigned short, (bf16)v.z);
        o.w = __builtin_bit_cast(unsigned short, (bf16)v.w);
        ((ushort4*)xb)[i] = o;
    } else if (bid < 7168) {
        int lb = bid - 4096;
        int bx = lb % 96, by = lb / 96;        // (NQKV/32, DMODEL/32)
        int tx = tid & 31, ty = tid >> 5;
        int r0 = by * 32, c0 = bx * 32;
#pragma unroll
        for (int i = 0; i < 4; i++)
            t[ty + i*8][tx] = w_qkv[(size_t)(r0 + ty + i*8) * NQKV + (c0 + tx)];
        __syncthreads();
#pragma unroll
        for (int i = 0; i < 4; i++) {
            int c = c0 + ty + i*8;
            int h = c / 192, f = c % 192;
            int cperm = ((f >> 6) << 10) + (h << 6) + (f & 63);
            wqkT[(size_t)cperm * DMODEL + (r0 + tx)] = (bf16)t[tx][ty + i*8];
        }
    } else {
        int lb = bid - 7168;
        int bx = lb & 31, by = lb >> 5;        // (DMODEL/32, DMODEL/32)
        int tx = tid & 31, ty = tid >> 5;
        int r0 = by * 32, c0 = bx * 32;
#pragma unroll
        for (int i = 0; i < 4; i++)
            t[ty + i*8][tx] = w_out[(size_t)(r0 + ty + i*8) * DMODEL + (c0 + tx)];
        __syncthreads();
#pragma unroll
        for (int i = 0; i < 4; i++)
            woT[(size_t)(c0 + ty + i*8) * DMODEL + (r0 + tx)] = (bf16)t[tx][ty + i*8];
    }
}

// ---------------- GEMM1: 256x192 tile, BK=64, 512 thr, counted-vmcnt (R16) ----
#define G1_NT 16   // 1024/64 K-tiles

__global__ __launch_bounds__(512, 2) void k_gemm_qkv(
        const bf16* __restrict__ A, const bf16* __restrict__ Bt,
        const float* __restrict__ bias,
        bf16* __restrict__ Q, bf16* __restrict__ Kp, bf16* __restrict__ Vt) {
    __shared__ __align__(16) bf16 As[2][256*64];
    __shared__ __align__(16) bf16 Bs[2][192*64];
    int tid = threadIdx.x;
    int wid = tid >> 6, lane = tid & 63;
    int wr = wid >> 2, wc = wid & 3;
    int g = lane >> 4, r = lane & 15;

    int lid = blockIdx.y * 16 + blockIdx.x;
    int swz = (lid & 7) * 32 + (lid >> 3);
    int tile_n = (swz % 16) * 192, tile_m = (swz / 16) * 256;

    f32x4 acc[8][3];
#pragma unroll
    for (int m = 0; m < 8; m++)
#pragma unroll
        for (int n = 0; n < 3; n++)
            acc[m][n] = (f32x4){0.f, 0.f, 0.f, 0.f};

    int srowA[4], schkA[4], srowB[3], schkB[3];
#pragma unroll
    for (int j2 = 0; j2 < 4; j2++) {
        int idx = tid + j2 * 512;
        srowA[j2] = idx >> 3;
        schkA[j2] = ((idx & 7) ^ (srowA[j2] & 7)) * 8;
    }
#pragma unroll
    for (int j2 = 0; j2 < 3; j2++) {
        int idx = tid + j2 * 512;
        srowB[j2] = idx >> 3;
        schkB[j2] = ((idx & 7) ^ (srowB[j2] & 7)) * 8;
    }

#define G1_STAGE(buf, k0)                                                          \
    {                                                                              \
        _Pragma("unroll")                                                          \
        for (int j2 = 0; j2 < 4; j2++)                                             \
            gload_lds16(A + (size_t)(tile_m + srowA[j2]) * DMODEL + (k0) + schkA[j2], \
                        As[buf] + (tid + j2*512) * 8);                             \
        _Pragma("unroll")                                                          \
        for (int j2 = 0; j2 < 3; j2++)                                             \
            gload_lds16(Bt + (size_t)(tile_n + srowB[j2]) * DMODEL + (k0) + schkB[j2], \
                        Bs[buf] + (tid + j2*512) * 8);                             \
    }

    G1_STAGE(0, 0);

    int r7 = r & 7;
    for (int t = 0; t < G1_NT; t++) {
        int cur = t & 1;
        if (t + 1 < G1_NT) {
            G1_STAGE(cur ^ 1, (t + 1) * 64);
            asm volatile("s_waitcnt vmcnt(7)" ::: "memory");
        } else {
            asm volatile("s_waitcnt vmcnt(0)" ::: "memory");
        }
        __builtin_amdgcn_s_barrier();
        __builtin_amdgcn_sched_barrier(0);

        const bf16* pa = As[cur];
        const bf16* pb = Bs[cur];
#pragma unroll
        for (int kk = 0; kk < 2; kk++) {
            int rchk = ((kk*4 + g) ^ r7) * 8;
            bf16x8 bfr[3];
#pragma unroll
            for (int n = 0; n < 3; n++)
                bfr[n] = ld_b8(pb + (wc*48 + n*16 + r) * 64 + rchk);
#pragma unroll
            for (int m = 0; m < 8; m++) {
                bf16x8 af = ld_b8(pa + (wr*128 + m*16 + r) * 64 + rchk);
#pragma unroll
                for (int n = 0; n < 3; n++)
                    acc[m][n] = __builtin_amdgcn_mfma_f32_16x16x32_bf16(af, bfr[n], acc[m][n], 0, 0, 0);
            }
        }
        asm volatile("s_waitcnt lgkmcnt(0)" ::: "memory");
        __builtin_amdgcn_s_barrier();
    }

#pragma unroll
    for (int m = 0; m < 8; m++) {
#pragma unroll
        for (int n = 0; n < 3; n++) {
            int col = tile_n + wc*48 + n*16 + r;
            int kind = col >> 10;
            int h = (col >> 6) & 15;
            int d = col & 63;
            float bv = bias[h*192 + (kind << 6) + d];
            if (kind == 2) {
                int row0 = tile_m + wr*128 + m*16 + g*4;
                int b = row0 >> 11, s0 = row0 & 2047;
                ushort4 vv;
                vv.x = __builtin_bit_cast(unsigned short, (bf16)(acc[m][n][0] + bv));
                vv.y = __builtin_bit_cast(unsigned short, (bf16)(acc[m][n][1] + bv));
                vv.z = __builtin_bit_cast(unsigned short, (bf16)(acc[m][n][2] + bv));
                vv.w = __builtin_bit_cast(unsigned short, (bf16)(acc[m][n][3] + bv));
                *(ushort4*)&Vt[(((size_t)(b*NH + h)) * DHEAD + d) * SEQ + s0] = vv;
            } else {
#pragma unroll
                for (int j = 0; j < 4; j++) {
                    int row = tile_m + wr*128 + m*16 + g*4 + j;
                    int b = row >> 11, s = row & 2047;
                    float v = acc[m][n][j] + bv;
                    size_t addr = (((size_t)(b*NH + h)) * SEQ + s) * DHEAD + d;
                    if (kind == 0) Q[addr]  = (bf16)(v * QSCALE);
                    else           Kp[addr] = (bf16)v;
                }
            }
        }
    }
#undef G1_STAGE
}

// ---- gemm_out: 64x128 tile, dbuf + counted vmcnt, grid 512 = 2/CU (R15) ----
__global__ __launch_bounds__(256) void k_gemm_out(
        const bf16* __restrict__ A, const bf16* __restrict__ Bt,
        const float* __restrict__ bias, float* __restrict__ out) {
    __shared__ __align__(16) bf16 As[2][64*32];
    __shared__ __align__(16) bf16 Bs[2][128*32];
    int tid = threadIdx.x;
    int wave = tid >> 6, lane = tid & 63;
    int g = lane >> 4, r = lane & 15;
    int srow = lane >> 2, schunk = (lane & 3) * 8;
    int tile_m = blockIdx.y * 64, tile_n = blockIdx.x * 128;

    f32x4 acc[4][2];
#pragma unroll
    for (int m = 0; m < 4; m++)
#pragma unroll
        for (int n = 0; n < 2; n++)
            acc[m][n] = (f32x4){0.f, 0.f, 0.f, 0.f};

#define GO_STAGE(buf, k0)                                                                 \
    {                                                                                     \
        gload_lds16(A  + (size_t)(tile_m + wave*16 + srow) * DMODEL + (k0) + schunk,      \
                    As[buf] + wave*512);                                                  \
        gload_lds16(Bt + (size_t)(tile_n + wave*16 + srow) * DMODEL + (k0) + schunk,      \
                    Bs[buf] + wave*512);                                                  \
        gload_lds16(Bt + (size_t)(tile_n + 64 + wave*16 + srow) * DMODEL + (k0) + schunk, \
                    Bs[buf] + 2048 + wave*512);                                           \
    }

    GO_STAGE(0, 0);

    for (int t = 0; t < 32; t++) {
        int cur = t & 1;
        if (t + 1 < 32) {
            GO_STAGE(cur ^ 1, (t + 1) * 32);
            asm volatile("s_waitcnt vmcnt(3)" ::: "memory");
        } else {
            asm volatile("s_waitcnt vmcnt(0)" ::: "memory");
        }
        __builtin_amdgcn_s_barrier();
        __builtin_amdgcn_sched_barrier(0);

        bf16x8 af[4], bfr[2];
#pragma unroll
        for (int m = 0; m < 4; m++) af[m]  = *(const bf16x8*)(As[cur] + (m*16 + r)*32 + g*8);
#pragma unroll
        for (int n = 0; n < 2; n++) bfr[n] = *(const bf16x8*)(Bs[cur] + (wave*32 + n*16 + r)*32 + g*8);
#pragma unroll
        for (int m = 0; m < 4; m++)
#pragma unroll
            for (int n = 0; n < 2; n++)
                acc[m][n] = __builtin_amdgcn_mfma_f32_16x16x32_bf16(af[m], bfr[n], acc[m][n], 0, 0, 0);
        asm volatile("s_waitcnt lgkmcnt(0)" ::: "memory");
        __builtin_amdgcn_s_barrier();
    }
#undef GO_STAGE

#pragma unroll
    for (int m = 0; m < 4; m++) {
#pragma unroll
        for (int n = 0; n < 2; n++) {
            int col = tile_n + wave*32 + n*16 + r;
            float bv = bias[col];
#pragma unroll
            for (int j = 0; j < 4; j++) {
                int row = tile_m + m*16 + g*4 + j;
                out[(size_t)row * DMODEL + col] = acc[m][n][j] + bv;
            }
        }
    }
}

// ---------------- flash attention: pad-72 LDS (43.4us plateau config) --------
#define QBLK 128
#define KVB 64

static __device__ __forceinline__ void attn_tile_body(
        const bf16* Ks, const bf16* VsT,
        const bf16x8 qa2[4], const bf16x8& ones,
        f32x16 o32[2], f32x16& acc_l,
        int kv0, int qb, int qrow, int l31, int hi, int lane) {
    const f32x16 z16 = {0,0,0,0,0,0,0,0,0,0,0,0,0,0,0,0};
    f32x16 st[2];
    st[0] = z16; st[1] = z16;
    __builtin_amdgcn_s_setprio(1);
#pragma unroll
    for (int c = 0; c < 4; c++) {
        bf16x8 kf0 = ld_b8(Ks + l31*KSTR        + c*16 + hi*8);
        bf16x8 kf1 = ld_b8(Ks + (32 + l31)*KSTR + c*16 + hi*8);
        st[0] = __builtin_amdgcn_mfma_f32_32x32x16_bf16(kf0, qa2[c], st[0], 0, 0, 0);
        st[1] = __builtin_amdgcn_mfma_f32_32x32x16_bf16(kf1, qa2[c], st[1], 0, 0, 0);
    }
    __builtin_amdgcn_s_setprio(0);

    bf16x8 vf[2][4];
#pragma unroll
    for (int dblk = 0; dblk < 2; dblk++)
#pragma unroll
        for (int c = 0; c < 4; c++)
            vf[dblk][c] = ld_b8(VsT + (dblk*32 + l31)*KSTR + c*16 + hi*8);

    bool needm = (kv0 + KVB - 1) > qb;
#pragma unroll
    for (int rb = 0; rb < 2; rb++) {
#pragma unroll
        for (int reg = 0; reg < 16; reg++) {
            float e = __builtin_amdgcn_exp2f(st[rb][reg]);
            if (needm) {
                int kv = kv0 + rb*32 + (reg & 3) + 8*(reg >> 2) + 4*hi;
                if (kv > qrow) e = 0.f;
            }
            st[rb][reg] = e;
        }
    }

    bf16x8 pa[4];
#pragma unroll
    for (int c = 0; c < 4; c++) {
        const f32x16& pp = st[c >> 1];
        const int base = (c & 1) * 8;
        uint32_t a0 = pk_bf16(pp[base+0], pp[base+1]);
        uint32_t a1 = pk_bf16(pp[base+2], pp[base+3]);
        uint32_t b0 = pk_bf16(pp[base+4], pp[base+5]);
        uint32_t b1 = pk_bf16(pp[base+6], pp[base+7]);
        u32x2 s0 = lane_swap32(a0, b0, lane);
        u32x2 s1 = lane_swap32(a1, b1, lane);
        uint4 fr = {s0.x, s1.x, s0.y, s1.y};
        pa[c] = __builtin_bit_cast(bf16x8, fr);
    }

    __builtin_amdgcn_s_setprio(1);
#pragma unroll
    for (int c = 0; c < 4; c++) {
        o32[0] = __builtin_amdgcn_mfma_f32_32x32x16_bf16(pa[c], vf[0][c], o32[0], 0, 0, 0);
        o32[1] = __builtin_amdgcn_mfma_f32_32x32x16_bf16(pa[c], vf[1][c], o32[1], 0, 0, 0);
        acc_l  = __builtin_amdgcn_mfma_f32_32x32x16_bf16(pa[c], ones, acc_l, 0, 0, 0);
    }
    __builtin_amdgcn_s_setprio(0);
}

// ---- equal-length job tables ----
__device__ const int8_t JQC[32]  = {10,10, 4, 0, 15,15, 3, 1,  9, 9, 7, 2, 13,14, 7, 5,
                                    14,14,11, 5, 15, 8,11, 6,  8,12,12, 6, 13,13,11,12};
__device__ const int8_t JT0[32]  = { 0,11, 0, 0,  0,11, 0, 0,  0,10, 0, 0,  0, 0, 8, 0,
                                    10,20, 0, 6, 22, 0, 8, 0,  9, 0, 9, 7, 10,19,16,18};
__device__ const int8_t JT1[32]  = {11,22,10, 2, 11,22, 8, 4, 10,20, 8, 6, 10,10,16, 6,
                                    20,30, 8,12, 32, 9,16, 7, 18, 9,18,14, 19,28,24,26};
__device__ const int8_t JSEG[32] = { 0, 1, 0, 0,  0, 1, 0, 0,  0, 1, 0, 0,  0, 0, 1, 0,
                                     1, 2, 0, 1,  2, 0, 1, 0,  1, 0, 1, 1,  1, 2, 2, 2};

__global__ __launch_bounds__(256) void k_attn_split(
        const bf16* __restrict__ Q, const bf16* __restrict__ K,
        const bf16* __restrict__ Vt,
        bf16* __restrict__ Op0, bf16* __restrict__ Op1, bf16* __restrict__ Op2,
        float* __restrict__ Lp0, float* __restrict__ Lp1, float* __restrict__ Lp2) {
    int scu = blockIdx.x;
    int bh = scu >> 3, slot = scu & 7;
    int j = slot * 4 + blockIdx.y;
    int qc  = JQC[j];
    int t0  = JT0[j];
    int t1  = JT1[j];
    int seg = JSEG[j];
    int q0 = qc * QBLK;
    int tid = threadIdx.x, wave = tid >> 6, lane = tid & 63;
    int l31 = lane & 31, hi = lane >> 5;

    __shared__ __align__(16) bf16 Ks[2][KVB*KSTR];
    __shared__ __align__(16) bf16 VsT[2][KVB*KSTR];

    const bf16* Kg = K  + (size_t)bh * SEQ * DHEAD;
    const bf16* Vg = Vt + (size_t)bh * DHEAD * SEQ;

    int qb = q0 + wave * 32;
    int qrow = qb + l31;

    const bf16* qrow_p = Q + ((size_t)bh * SEQ + qrow) * DHEAD;
    bf16x8 qa2[4];
#pragma unroll
    for (int c = 0; c < 4; c++) qa2[c] = ld_b8(qrow_p + c*16 + hi*8);

    bf16x8 ones;
#pragma unroll
    for (int c = 0; c < 8; c++) ones[c] = (bf16)1.0f;

    const f32x16 z16 = {0,0,0,0,0,0,0,0,0,0,0,0,0,0,0,0};
    f32x16 o32[2], acc_l;
    o32[0] = z16; o32[1] = z16; acc_l = z16;

    int qmax_wave = qb + 31;

    int srow = tid >> 3, sc8 = (tid & 7) * 8;
    int wK0 = srow*KSTR + sc8;
    int wK1 = (srow+32)*KSTR + sc8;

    bf16x8 kreg[2], vreg[2];
    {
        int kvs = t0 * KVB;
        kreg[0] = ld_b8(Kg + (size_t)(kvs + srow)      * DHEAD + sc8);
        kreg[1] = ld_b8(Kg + (size_t)(kvs + srow + 32) * DHEAD + sc8);
        vreg[0] = ld_b8(Vg + (size_t)srow      * SEQ + kvs + sc8);
        vreg[1] = ld_b8(Vg + (size_t)(srow+32) * SEQ + kvs + sc8);
    }

    int cur = 0;
    for (int t = t0; t < t1; t++) {
        int kv0 = t * KVB;
        *(uint4*)&Ks[cur][wK0]  = __builtin_bit_cast(uint4, kreg[0]);
        *(uint4*)&Ks[cur][wK1]  = __builtin_bit_cast(uint4, kreg[1]);
        *(uint4*)&VsT[cur][wK0] = __builtin_bit_cast(uint4, vreg[0]);
        *(uint4*)&VsT[cur][wK1] = __builtin_bit_cast(uint4, vreg[1]);
        __syncthreads();

        if (t + 1 < t1) {
            int kv1 = kv0 + KVB;
            kreg[0] = ld_b8(Kg + (size_t)(kv1 + srow)      * DHEAD + sc8);
            kreg[1] = ld_b8(Kg + (size_t)(kv1 + srow + 32) * DHEAD + sc8);
            vreg[0] = ld_b8(Vg + (size_t)srow      * SEQ + kv1 + sc8);
            vreg[1] = ld_b8(Vg + (size_t)(srow+32) * SEQ + kv1 + sc8);
        }

        if (kv0 <= qmax_wave)
            attn_tile_body(Ks[cur], VsT[cur], qa2, ones, o32, acc_l,
                           kv0, qb, qrow, l31, hi, lane);
        cur ^= 1;
    }

    bf16* Op; float* Lp; size_t obase; int lbase;
    if (seg == 0)      { Op = Op0; Lp = Lp0; obase = ((size_t)bh*2048 + q0) * 64;          lbase = bh*2048 + q0; }
    else if (seg == 1) { Op = Op1; Lp = Lp1; obase = ((size_t)bh*1408 + (qc-5)*128) * 64;  lbase = bh*1408 + (qc-5)*128; }
    else               { Op = Op2; Lp = Lp2; obase = ((size_t)bh*640  + (qc-11)*128) * 64; lbase = bh*640  + (qc-11)*128; }

    if (l31 == 0) {
#pragma unroll
        for (int reg = 0; reg < 16; reg++) {
            int qr = (reg & 3) + 8*(reg >> 2) + 4*hi;
            Lp[lbase + wave*32 + qr] = acc_l[reg];
        }
    }

#pragma unroll
    for (int reg = 0; reg < 16; reg++) {
        int qr = (reg & 3) + 8*(reg >> 2) + 4*hi;
        size_t base = obase + (size_t)(wave*32 + qr) * 64 + l31;
        Op[base]      = (bf16)o32[0][reg];
        Op[base + 32] = (bf16)o32[1][reg];
    }
}

// ---- merge: attn[b][s][h][d] = (sum of 1..3 partials)/(sum of l) ----
__global__ __launch_bounds__(256) void k_merge(
        const bf16* __restrict__ Op0, const bf16* __restrict__ Op1,
        const bf16* __restrict__ Op2,
        const float* __restrict__ Lp0, const float* __restrict__ Lp1,
        const float* __restrict__ Lp2,
        bf16* __restrict__ Oa) {
    int g = blockIdx.x * 256 + threadIdx.x;      // 524288 total
    int dseg = g & 7;
    int s = (g >> 3) & 2047;
    int bh = g >> 14;
    int qc = s >> 7;
    int sl = s & 127;

    size_t r0 = ((size_t)bh * 2048 + s) * 64 + dseg*8;
    bf16x8 p0 = ld_b8(Op0 + r0);
    float l = Lp0[bh*2048 + s];
    float acc[8];
#pragma unroll
    for (int i = 0; i < 8; i++) acc[i] = (float)p0[i];

    if (qc >= 5) {
        size_t r1 = ((size_t)bh * 1408 + (qc-5)*128 + sl) * 64 + dseg*8;
        bf16x8 p1 = ld_b8(Op1 + r1);
        l += Lp1[bh*1408 + (qc-5)*128 + sl];
#pragma unroll
        for (int i = 0; i < 8; i++) acc[i] += (float)p1[i];
        if (qc >= 11) {
            size_t r2 = ((size_t)bh * 640 + (qc-11)*128 + sl) * 64 + dseg*8;
            bf16x8 p2 = ld_b8(Op2 + r2);
            l += Lp2[bh*640 + (qc-11)*128 + sl];
#pragma unroll
            for (int i = 0; i < 8; i++) acc[i] += (float)p2[i];
        }
    }

    float inv = 1.0f / l;
    bf16x8 r;
#pragma unroll
    for (int i = 0; i < 8; i++) r[i] = (bf16)(acc[i] * inv);
    int b = bh >> 4, h = bh & 15;
    *(uint4*)&Oa[(((size_t)b * SEQ + s) * NH + h) * DHEAD + dseg*8] =
        __builtin_bit_cast(uint4, r);
}

// ---- fallback single-pass attention for small ws ----
__global__ __launch_bounds__(256) void k_attn(
        const bf16* __restrict__ Q, const bf16* __restrict__ K,
        const bf16* __restrict__ Vt, bf16* __restrict__ O) {
    int bh = blockIdx.y;
    int qc = (bh >= 16) ? (15 - (int)blockIdx.x) : (int)blockIdx.x;
    int q0 = qc * QBLK;
    int tid = threadIdx.x, wave = tid >> 6, lane = tid & 63;
    int l31 = lane & 31, hi = lane >> 5;

    __shared__ __align__(16) bf16 Ks[2][KVB*KSTR];
    __shared__ __align__(16) bf16 VsT[2][KVB*KSTR];

    const bf16* Kg = K  + (size_t)bh * SEQ * DHEAD;
    const bf16* Vg = Vt + (size_t)bh * DHEAD * SEQ;

    int qb = q0 + wave * 32;
    int qrow = qb + l31;

    const bf16* qrow_p = Q + ((size_t)bh * SEQ + qrow) * DHEAD;
    bf16x8 qa2[4];
#pragma unroll
    for (int c = 0; c < 4; c++) qa2[c] = ld_b8(qrow_p + c*16 + hi*8);

    bf16x8 ones;
#pragma unroll
    for (int c = 0; c < 8; c++) ones[c] = (bf16)1.0f;

    const f32x16 z16 = {0,0,0,0,0,0,0,0,0,0,0,0,0,0,0,0};
    f32x16 o32[2], acc_l;
    o32[0] = z16; o32[1] = z16; acc_l = z16;

    int nt = 2*qc + 2;
    int qmax_wave = qb + 31;

    int srow = tid >> 3, sc8 = (tid & 7) * 8;
    int wK0 = srow*KSTR + sc8;
    int wK1 = (srow+32)*KSTR + sc8;

    bf16x8 kreg[2], vreg[2];
    kreg[0] = ld_b8(Kg + (size_t)srow      * DHEAD + sc8);
    kreg[1] = ld_b8(Kg + (size_t)(srow+32) * DHEAD + sc8);
    vreg[0] = ld_b8(Vg + (size_t)srow      * SEQ + sc8);
    vreg[1] = ld_b8(Vg + (size_t)(srow+32) * SEQ + sc8);

    int cur = 0;
    for (int t = 0; t < nt; t++) {
        int kv0 = t * KVB;
        *(uint4*)&Ks[cur][wK0]  = __builtin_bit_cast(uint4, kreg[0]);
        *(uint4*)&Ks[cur][wK1]  = __builtin_bit_cast(uint4, kreg[1]);
        *(uint4*)&VsT[cur][wK0] = __builtin_bit_cast(uint4, vreg[0]);
        *(uint4*)&VsT[cur][wK1] = __builtin_bit_cast(uint4, vreg[1]);
        __syncthreads();

        if (t + 1 < nt) {
            int kv1 = kv0 + KVB;
            kreg[0] = ld_b8(Kg + (size_t)(kv1 + srow)      * DHEAD + sc8);
            kreg[1] = ld_b8(Kg + (size_t)(kv1 + srow + 32) * DHEAD + sc8);
            vreg[0] = ld_b8(Vg + (size_t)srow      * SEQ + kv1 + sc8);
            vreg[1] = ld_b8(Vg + (size_t)(srow+32) * SEQ + kv1 + sc8);
        }

        if (kv0 <= qmax_wave)
            attn_tile_body(Ks[cur], VsT[cur], qa2, ones, o32, acc_l,
                           kv0, qb, qrow, l31, hi, lane);
        cur ^= 1;
    }

    int b = bh >> 4, h = bh & 15;
#pragma unroll
    for (int reg = 0; reg < 16; reg++) {
        int qr = (reg & 3) + 8*(reg >> 2) + 4*hi;
        int srow2 = q0 + wave*32 + qr;
        float linv = 1.0f / acc_l[reg];
        size_t base = (((size_t)b * SEQ + srow2) * NH + h) * DHEAD + l31;
        O[base]      = (bf16)(o32[0][reg] * linv);
        O[base + 32] = (bf16)(o32[1][reg] * linv);
    }
}

// ---------------- launch ----------------

extern "C" void kernel_launch(void* const* d_in, const int* in_sizes, int n_in,
                              void* d_out, int out_size, void* d_ws, size_t ws_size,
                              hipStream_t stream) {
    const float* x     = (const float*)d_in[0];
    const float* w_qkv = (const float*)d_in[1];
    const float* b_qkv = (const float*)d_in[2];
    const float* w_out = (const float*)d_in[3];
    const float* b_out = (const float*)d_in[4];
    float* out = (float*)d_out;

    char* ws = (char*)d_ws;
    bf16* xb   = (bf16*)(ws);                      // 8.39MB; later attn output
    bf16* wqkT = (bf16*)(ws + 8388608);            // 6.29MB (dead after GEMM1 -> Lp)
    bf16* woT  = (bf16*)(ws + 14680064);           // 2.10MB
    bf16* qb   = (bf16*)(ws + 16777216);           // 8.39MB
    bf16* kb   = (bf16*)(ws + 25165824);           // 8.39MB
    bf16* vb   = (bf16*)(ws + 33554432);           // 8.39MB (V^T layout)
    bf16* Op0  = (bf16*)(ws + 41943040);           // 8.39MB (seg0, all qc)
    bf16* Op1  = (bf16*)(ws + 50331648);           // 5.77MB (seg1, qc>=5)
    bf16* Op2  = (bf16*)(ws + 56098816);           // 2.62MB (seg2, qc>=11)
    float* Lp0 = (float*)(ws + 8388608);           // in dead wqkT region
    float* Lp1 = (float*)(ws + 8388608 + 262144);
    float* Lp2 = (float*)(ws + 8388608 + 524288);
    const size_t WS_NEED = 58720256;
    bf16* attn = xb;                               // reuse x_bf16 region

    k_prep<<<8192, 256, 0, stream>>>(x, w_qkv, w_out, xb, wqkT, woT);

    k_gemm_qkv<<<dim3(16, 16), 512, 0, stream>>>(xb, wqkT, b_qkv, qb, kb, vb);

    if (ws_size >= WS_NEED) {
        k_attn_split<<<dim3(256, 4), 256, 0, stream>>>(qb, kb, vb,
                                                       Op0, Op1, Op2, Lp0, Lp1, Lp2);
        k_merge<<<(NBS*NH*SEQ*DHEAD/8)/256, 256, 0, stream>>>(Op0, Op1, Op2,
                                                              Lp0, Lp1, Lp2, attn);
    } else {
        k_attn<<<dim3(SEQ/QBLK, NBS*NH), 256, 0, stream>>>(qb, kb, vb, attn);
    }

    k_gemm_out<<<dim3(DMODEL/128, MROWS/64), 256, 0, stream>>>(attn, woT, b_out, out);
}